// Round 2
// baseline (445.592 us; speedup 1.0000x reference)
//
#include <hip/hip_runtime.h>

#define IN_F 8192
#define OUT_F 8192
#define NBATCH 16
#define KC 512              // K-chunk staged in LDS
#define NG 64               // scale groups along IN (group size 128)
#define KSPLIT 2
#define KRANGE (IN_F / KSPLIT)   // 4096 per block

// out[b, o] = bias[o]  (atomic partials added on top by main kernel)
__global__ __launch_bounds__(256)
void init_out_kernel(const float* __restrict__ bias, float* __restrict__ out) {
    const int i = blockIdx.x * 256 + threadIdx.x;   // i < 16*8192
    out[i] = bias[i & (OUT_F - 1)];
}

// block = 256 threads = 4 waves; each wave owns 4 output rows; lanes split K.
// grid = (OUT_F/16, KSPLIT) = (512, 2) -> 4 blocks/CU, 16 waves/CU.
__global__ __launch_bounds__(256, 4)
void axcore_dsew_linear_kernel(const float* __restrict__ x,
                               const float* __restrict__ w,
                               const float* __restrict__ scale,
                               float* __restrict__ out) {
    __shared__ __align__(16) float xlds[NBATCH * KC];   // 32 KB, [b][k] (stride KC)

    const int t    = threadIdx.x;
    const int wv   = __builtin_amdgcn_readfirstlane(t >> 6);  // wave id, force uniform
    const int lane = t & 63;
    const int o0   = blockIdx.x * 16 + wv * 4;   // this wave's 4 output rows
    const int k0   = blockIdx.y * KRANGE;

    float acc[4][NBATCH];
#pragma unroll
    for (int r = 0; r < 4; ++r)
#pragma unroll
        for (int b = 0; b < NBATCH; ++b) acc[r][b] = 0.f;

    for (int kc = k0; kc < k0 + KRANGE; kc += KC) {
        // ---- barrier 1: previous chunk's LDS reads are done ----
        __syncthreads();

        // ---- issue w loads NOW so their HBM latency overlaps x-staging;
        //      barrier 2's vmcnt drain waits on both in the same window ----
        float4 wq[2][4];
#pragma unroll
        for (int s = 0; s < 2; ++s)
#pragma unroll
            for (int r = 0; r < 4; ++r)
                wq[s][r] = *(const float4*)&w[(size_t)(o0 + r) * IN_F + kc + s * 256 + 4 * lane];

        // ---- scales: wave-uniform addresses -> s_load; select by half-wave ----
        // group of k = kc + s*256 + 4*lane is g0 + 2*s + (lane>=32)
        const int g0 = kc >> 7;
        float sc[2][4];
#pragma unroll
        for (int s = 0; s < 2; ++s)
#pragma unroll
            for (int r = 0; r < 4; ++r) {
                const float sa = scale[(o0 + r) * NG + g0 + 2 * s];
                const float sb = scale[(o0 + r) * NG + g0 + 2 * s + 1];
                sc[s][r] = (lane < 32) ? sa : sb;
            }

        // ---- stage x[0:16, kc:kc+KC] into LDS as [b][k] (concurrent w/ w loads) ----
#pragma unroll
        for (int p = 0; p < 8; ++p) {
            const int fidx = p * 256 + t;       // float4 index in [0, 2048)
            const int bb = fidx >> 7;           // batch
            const int kq = fidx & 127;          // float4 within row
            *(float4*)&xlds[bb * KC + 4 * kq] =
                *(const float4*)&x[bb * IN_F + kc + 4 * kq];
        }
        __syncthreads();   // barrier 2: x staged AND w arrived

        // ---- compute: no memory stalls left except LDS reads ----
#pragma unroll
        for (int s = 0; s < 2; ++s) {
            const int klocal = s * 256 + 4 * lane;
            float4 wr[4];
#pragma unroll
            for (int r = 0; r < 4; ++r) {
                wr[r].x = wq[s][r].x * sc[s][r];
                wr[r].y = wq[s][r].y * sc[s][r];
                wr[r].z = wq[s][r].z * sc[s][r];
                wr[r].w = wq[s][r].w * sc[s][r];
            }
#pragma unroll
            for (int b = 0; b < NBATCH; ++b) {
                const float4 xv = *(const float4*)&xlds[b * KC + klocal];
#pragma unroll
                for (int r = 0; r < 4; ++r) {
                    acc[r][b] += wr[r].x * xv.x;
                    acc[r][b] += wr[r].y * xv.y;
                    acc[r][b] += wr[r].z * xv.z;
                    acc[r][b] += wr[r].w * xv.w;
                }
            }
        }
    }

    // ---- epilogue: butterfly-reduce across 64 lanes, atomic-add partial ----
#pragma unroll
    for (int r = 0; r < 4; ++r) {
        const int o = o0 + r;
#pragma unroll
        for (int b = 0; b < NBATCH; ++b) {
            float v = acc[r][b];
            v += __shfl_xor(v, 1);
            v += __shfl_xor(v, 2);
            v += __shfl_xor(v, 4);
            v += __shfl_xor(v, 8);
            v += __shfl_xor(v, 16);
            v += __shfl_xor(v, 32);
            if (lane == 0) atomicAdd(&out[b * OUT_F + o], v);
        }
    }
}

extern "C" void kernel_launch(void* const* d_in, const int* in_sizes, int n_in,
                              void* d_out, int out_size, void* d_ws, size_t ws_size,
                              hipStream_t stream) {
    const float* x    = (const float*)d_in[0];
    const float* w    = (const float*)d_in[1];
    const float* sc   = (const float*)d_in[2];
    const float* bias = (const float*)d_in[3];
    // d_in[4] = types: constant lookup in the reference, no float math -> unused
    float* out = (float*)d_out;

    hipLaunchKernelGGL(init_out_kernel, dim3(NBATCH * OUT_F / 256), dim3(256),
                       0, stream, bias, out);
    hipLaunchKernelGGL(axcore_dsew_linear_kernel, dim3(OUT_F / 16, KSPLIT), dim3(256),
                       0, stream, x, w, sc, out);
}

// Round 3
// 403.030 us; speedup vs baseline: 1.1056x; 1.1056x over previous
//
#include <hip/hip_runtime.h>
#include <hip/hip_bf16.h>

#define IN_F 8192
#define OUT_F 8192
#define NB 16
#define NG 64                  // scale groups (group = 128)
#define KSPLIT 8
#define KRANGE (IN_F / KSPLIT) // 1024 K per block
#define NSTEP (KRANGE / 32)    // 32 MFMA K-steps per block

typedef __attribute__((ext_vector_type(8))) short bf16x8;
typedef __attribute__((ext_vector_type(4))) float f32x4;

static __device__ __forceinline__ short f2bf(float f) {
    __hip_bfloat16 h = __float2bfloat16(f);
    return *reinterpret_cast<short*>(&h);
}

// out[b,o] = bias[o]; main kernel atomically adds K-split partials on top.
__global__ __launch_bounds__(256)
void init_out_kernel(const float* __restrict__ bias, float* __restrict__ out) {
    const int i = blockIdx.x * 256 + threadIdx.x;
    out[i] = bias[i & (OUT_F - 1)];
}

// block = 256 thr = 4 waves; wave = one 16x16 MFMA tile (16 batches x 16 rows).
// grid = (OUT_F/64, KSPLIT) = (128, 8) -> 1024 blocks = 4/CU.
// K-loop has NO barriers: x staged once (A-frag-swizzled bf16), w streamed
// global->reg->dequant->bf16->MFMA.
__global__ __launch_bounds__(256, 4)
void axcore_mfma_kernel(const float* __restrict__ x,
                        const float* __restrict__ w,
                        const float* __restrict__ scale,
                        float* __restrict__ out) {
    // [t][lane][j] bf16: A-fragment order. 32*64*8*2 B = 32 KB.
    __shared__ __align__(16) unsigned short xswz[NSTEP * 64 * 8];

    const int t    = threadIdx.x;
    const int wv   = t >> 6;
    const int lane = t & 63;
    const int k0   = blockIdx.y * KRANGE;
    const int o0   = blockIdx.x * 64 + wv * 16;

    // ---- stage x[0:16][k0:k0+KRANGE] -> bf16, swizzled to A-frag layout ----
    // element (m, klocal): t=klocal>>5, ln=m+16*((klocal&31)>>3), j=klocal&7
#pragma unroll
    for (int p = 0; p < 16; ++p) {
        const int idx = p * 256 + t;        // float4 id in [0, 4096)
        const int m   = idx >> 8;           // batch
        const int k4  = (idx & 255) * 4;    // klocal, multiple of 4
        const float4 v = *(const float4*)&x[m * IN_F + k0 + k4];
        const int tt = k4 >> 5;
        const int ln = m + 16 * ((k4 & 31) >> 3);
        const int jj = k4 & 7;              // 0 or 4 -> 8B-aligned dest
        ushort4 sv;
        sv.x = (unsigned short)f2bf(v.x);
        sv.y = (unsigned short)f2bf(v.y);
        sv.z = (unsigned short)f2bf(v.z);
        sv.w = (unsigned short)f2bf(v.w);
        *(ushort4*)&xswz[(tt * 64 + ln) * 8 + jj] = sv;
    }
    __syncthreads();   // the only barrier

    // ---- B-operand geometry: lane holds B[n=lane&15][k=(lane>>4)*8 + j] ----
    const int nrow = o0 + (lane & 15);
    const int koct = (lane >> 4) * 8;
    const float* wrow = &w[(size_t)nrow * IN_F];

    // prefetch this lane's 8 group scales (row nrow, groups k0/128 .. +7)
    const float4 sA = *(const float4*)&scale[nrow * NG + (k0 >> 7)];
    const float4 sB = *(const float4*)&scale[nrow * NG + (k0 >> 7) + 4];
    float sg[8] = {sA.x, sA.y, sA.z, sA.w, sB.x, sB.y, sB.z, sB.w};

    f32x4 acc = {0.f, 0.f, 0.f, 0.f};

#pragma unroll 2
    for (int gi = 0; gi < KRANGE / 128; ++gi) {   // 8 scale-groups
        const float s = sg[gi];
#pragma unroll
        for (int ts = 0; ts < 4; ++ts) {
            const int tt = gi * 4 + ts;
            const int kg = k0 + tt * 32 + koct;
            const float4 w0 = *(const float4*)&wrow[kg];
            const float4 w1 = *(const float4*)&wrow[kg + 4];

            bf16x8 bfrag;
            bfrag[0] = f2bf(w0.x * s);
            bfrag[1] = f2bf(w0.y * s);
            bfrag[2] = f2bf(w0.z * s);
            bfrag[3] = f2bf(w0.w * s);
            bfrag[4] = f2bf(w1.x * s);
            bfrag[5] = f2bf(w1.y * s);
            bfrag[6] = f2bf(w1.z * s);
            bfrag[7] = f2bf(w1.w * s);

            // conflict-free: byte addr = tt*1024 + lane*16
            const bf16x8 afrag = *(const bf16x8*)&xswz[(tt * 64 + lane) * 8];

            acc = __builtin_amdgcn_mfma_f32_16x16x32_bf16(afrag, bfrag, acc,
                                                          0, 0, 0);
        }
    }

    // ---- epilogue: D[col=lane&15 -> out row nrow][row=(lane>>4)*4+reg -> batch]
#pragma unroll
    for (int r = 0; r < 4; ++r) {
        const int b = (lane >> 4) * 4 + r;
        atomicAdd(&out[b * OUT_F + nrow], acc[r]);
    }
}

extern "C" void kernel_launch(void* const* d_in, const int* in_sizes, int n_in,
                              void* d_out, int out_size, void* d_ws, size_t ws_size,
                              hipStream_t stream) {
    const float* x    = (const float*)d_in[0];
    const float* w    = (const float*)d_in[1];
    const float* sc   = (const float*)d_in[2];
    const float* bias = (const float*)d_in[3];
    // d_in[4] = types: constant lookup, no float math -> unused
    float* out = (float*)d_out;

    hipLaunchKernelGGL(init_out_kernel, dim3(NB * OUT_F / 256), dim3(256),
                       0, stream, bias, out);
    hipLaunchKernelGGL(axcore_mfma_kernel, dim3(OUT_F / 64, KSPLIT), dim3(256),
                       0, stream, x, w, sc, out);
}

// Round 4
// 395.791 us; speedup vs baseline: 1.1258x; 1.0183x over previous
//
#include <hip/hip_runtime.h>
#include <hip/hip_bf16.h>

#define IN_F 8192
#define OUT_F 8192
#define NB 16
#define NG 64                  // scale groups (group = 128)
#define KSPLIT 8
#define KRANGE (IN_F / KSPLIT) // 1024 K per block
#define NSTEP (KRANGE / 32)    // 32 MFMA K-steps per block
#define PF 8                   // software-pipeline depth (steps)

typedef __attribute__((ext_vector_type(8))) short bf16x8;
typedef __attribute__((ext_vector_type(4))) float f32x4;

// pack 2 floats -> 2 bf16 (round-half-away): 2 adds + 1 v_perm_b32
static __device__ __forceinline__ unsigned bfpack2(float a, float b) {
    unsigned ua = __float_as_uint(a) + 0x8000u;
    unsigned ub = __float_as_uint(b) + 0x8000u;
    // result bytes: [0,1] = ua bytes [2,3] (S1), [2,3] = ub bytes [2,3] (S0)
    return __builtin_amdgcn_perm(ub, ua, 0x07060302u);
}

// out[b,o] = bias[o]; main kernel atomically adds K-split partials on top.
__global__ __launch_bounds__(256)
void init_out_kernel(const float* __restrict__ bias, float* __restrict__ out) {
    const int i = blockIdx.x * 256 + threadIdx.x;
    out[i] = bias[i & (OUT_F - 1)];
}

// block = 256 thr = 4 waves; wave = one 16x16 MFMA tile (16 batches x 16 rows).
// grid = (OUT_F/64, KSPLIT) = (128, 8) -> 1024 blocks = 4/CU, 16 waves/CU.
// K-loop: barrier-free, 8-step register pipeline on the w stream.
__global__ __launch_bounds__(256, 4)
void axcore_mfma_kernel(const float* __restrict__ x,
                        const float* __restrict__ w,
                        const float* __restrict__ scale,
                        float* __restrict__ out) {
    // A-fragment-swizzled bf16 x: [step][lane][j]. 32*64*8*2 B = 32 KB.
    __shared__ __align__(16) unsigned short xswz[NSTEP * 64 * 8];

    const int t    = threadIdx.x;
    const int lane = t & 63;
    const int k0   = blockIdx.y * KRANGE;
    const int o0   = blockIdx.x * 64 + (t >> 6) * 16;

    // ---- stage x[0:16][k0:k0+KRANGE] -> bf16, swizzled to A-frag order ----
#pragma unroll
    for (int p = 0; p < 16; ++p) {
        const int idx = p * 256 + t;        // float4 id in [0, 4096)
        const int m   = idx >> 8;           // batch (== p)
        const int k4  = (idx & 255) * 4;    // klocal, multiple of 4
        const float4 v = *(const float4*)&x[m * IN_F + k0 + k4];
        const int tt = k4 >> 5;
        const int ln = m + 16 * ((k4 & 31) >> 3);
        const int jj = k4 & 7;              // 0 or 4
        uint2 sv;
        sv.x = bfpack2(v.x, v.y);
        sv.y = bfpack2(v.z, v.w);
        *(uint2*)&xswz[(tt * 64 + ln) * 8 + jj] = sv;
    }
    __syncthreads();   // the only barrier

    // ---- B-operand geometry: lane holds B[n=lane&15][k=(lane>>4)*8 + j] ----
    const int nrow = o0 + (lane & 15);
    const int koct = (lane >> 4) * 8;
    const float* wrow = &w[(size_t)nrow * IN_F + k0 + koct];

    // 8 group scales for this row/chunk (constant-indexed after full unroll)
    const float4 sA = *(const float4*)&scale[nrow * NG + (k0 >> 7)];
    const float4 sB = *(const float4*)&scale[nrow * NG + (k0 >> 7) + 4];
    const float sg[8] = {sA.x, sA.y, sA.z, sA.w, sB.x, sB.y, sB.z, sB.w};

    // ---- prologue: fill 8-step pipeline (16 loads, 8 KB in flight) ----
    float4 wbuf0[PF], wbuf1[PF];
#pragma unroll
    for (int i = 0; i < PF; ++i) {
        wbuf0[i] = *(const float4*)&wrow[i * 32];
        wbuf1[i] = *(const float4*)&wrow[i * 32 + 4];
    }

    f32x4 acc = {0.f, 0.f, 0.f, 0.f};

#pragma unroll
    for (int ts = 0; ts < NSTEP; ++ts) {
        const float4 w0 = wbuf0[ts % PF];
        const float4 w1 = wbuf1[ts % PF];
        if (ts + PF < NSTEP) {
            wbuf0[ts % PF] = *(const float4*)&wrow[(ts + PF) * 32];
            wbuf1[ts % PF] = *(const float4*)&wrow[(ts + PF) * 32 + 4];
        }
        const float s = sg[ts / 4];   // constant index (fully unrolled)

        bf16x8 bfrag;
        unsigned* bu = (unsigned*)&bfrag;
        bu[0] = bfpack2(w0.x * s, w0.y * s);
        bu[1] = bfpack2(w0.z * s, w0.w * s);
        bu[2] = bfpack2(w1.x * s, w1.y * s);
        bu[3] = bfpack2(w1.z * s, w1.w * s);

        // conflict-free ds_read_b128: byte addr = ts*1024 + lane*16
        const bf16x8 afrag = *(const bf16x8*)&xswz[(ts * 64 + lane) * 8];

        acc = __builtin_amdgcn_mfma_f32_16x16x32_bf16(afrag, bfrag, acc, 0, 0, 0);
    }

    // ---- epilogue: D[col=lane&15 -> row nrow][reg r -> batch (lane>>4)*4+r]
#pragma unroll
    for (int r = 0; r < 4; ++r) {
        const int b = (lane >> 4) * 4 + r;
        atomicAdd(&out[b * OUT_F + nrow], acc[r]);
    }
}

extern "C" void kernel_launch(void* const* d_in, const int* in_sizes, int n_in,
                              void* d_out, int out_size, void* d_ws, size_t ws_size,
                              hipStream_t stream) {
    const float* x    = (const float*)d_in[0];
    const float* w    = (const float*)d_in[1];
    const float* sc   = (const float*)d_in[2];
    const float* bias = (const float*)d_in[3];
    // d_in[4] = types: constant lookup, no float math -> unused
    float* out = (float*)d_out;

    hipLaunchKernelGGL(init_out_kernel, dim3(NB * OUT_F / 256), dim3(256),
                       0, stream, bias, out);
    hipLaunchKernelGGL(axcore_mfma_kernel, dim3(OUT_F / 64, KSPLIT), dim3(256),
                       0, stream, x, w, sc, out);
}

// Round 5
// 376.634 us; speedup vs baseline: 1.1831x; 1.0509x over previous
//
#include <hip/hip_runtime.h>
#include <hip/hip_bf16.h>

#define IN_F 8192
#define OUT_F 8192
#define NB 16
#define NG 64                    // scale groups (group = 128)
#define KSPLIT 16
#define KRANGE (IN_F / KSPLIT)   // 512 K per block
#define BK 256                   // K per staged w chunk
#define NCHUNK (KRANGE / BK)     // 2
#define NSTEP (KRANGE / 32)      // 16 MFMA K-steps per block
#define WSTRIDE 264              // ushorts per LDS w row: 256 bf16 + 8 pad (528 B)

typedef __attribute__((ext_vector_type(8))) short bf16x8;
typedef __attribute__((ext_vector_type(4))) float f32x4;

// pack 2 floats -> 2 bf16 (round-half-away): 2 adds + 1 v_perm_b32
static __device__ __forceinline__ unsigned bfpack2(float a, float b) {
    unsigned ua = __float_as_uint(a) + 0x8000u;
    unsigned ub = __float_as_uint(b) + 0x8000u;
    return __builtin_amdgcn_perm(ub, ua, 0x07060302u);  // lo=bf16(a), hi=bf16(b)
}

// out[b,o] = bias[o]; main kernel atomically adds K-split partials on top.
__global__ __launch_bounds__(256)
void init_out_kernel(const float* __restrict__ bias, float* __restrict__ out) {
    const int i = blockIdx.x * 256 + threadIdx.x;
    out[i] = bias[i & (OUT_F - 1)];
}

// block = 256 thr = 4 waves; wave = one 16x16 tile (16 batches x 16 out rows).
// grid = (OUT_F/64, KSPLIT) = (128, 16). LDS 50 KB -> 3 blocks/CU, 12 waves/CU.
// All w global loads are 1 KB contiguous from a single row (one wave-instr per
// row-chunk); the B-fragment scatter happens in LDS, not at HBM.
__global__ __launch_bounds__(256, 3)
void axcore_mfma_kernel(const float* __restrict__ x,
                        const float* __restrict__ w,
                        const float* __restrict__ scale,
                        float* __restrict__ out) {
    __shared__ __align__(16) unsigned short xswz[NSTEP * 64 * 8];   // 16 KB
    __shared__ __align__(16) unsigned short wlds[64 * WSTRIDE];     // 33 KB

    const int t    = threadIdx.x;
    const int wv   = t >> 6;
    const int lane = t & 63;
    const int k0   = blockIdx.y * KRANGE;
    const int ob   = blockIdx.x * 64;           // block's first out row
    const int o0   = ob + wv * 16;              // wave's first out row

    // ---- stage x[0:16][k0:k0+512] -> bf16, A-frag swizzled ----
    // elem (m, kl): tt=kl>>5, ln=m+16*((kl&31)>>3), j=kl&7
#pragma unroll
    for (int p = 0; p < 8; ++p) {
        const int idx = p * 256 + t;            // float4 id in [0, 2048)
        const int m   = idx >> 7;               // batch
        const int k4  = (idx & 127) * 4;        // klocal
        const float4 v = *(const float4*)&x[m * IN_F + k0 + k4];
        const int tt = k4 >> 5;
        const int ln = m + 16 * ((k4 & 31) >> 3);
        const int jj = k4 & 7;                  // 0 or 4
        uint2 sv;
        sv.x = bfpack2(v.x, v.y);
        sv.y = bfpack2(v.z, v.w);
        *(uint2*)&xswz[(tt * 64 + ln) * 8 + jj] = sv;
    }

    f32x4 acc = {0.f, 0.f, 0.f, 0.f};
    const int nrow = o0 + (lane & 15);          // this lane's out row (B n-index)

#pragma unroll
    for (int c = 0; c < NCHUNK; ++c) {
        if (c > 0) __syncthreads();             // prev chunk's frag reads done

        // ---- stage w chunk: wave wv stages rows wv*16..+15, 1 KB contiguous
        //      per instruction; dequant + bf16-pack in flight ----
        const int kcg = k0 + c * BK;            // chunk's global k base
        const int gb  = kcg >> 7;               // first scale group of chunk
#pragma unroll
        for (int i = 0; i < 16; ++i) {
            const int rl  = wv * 16 + i;        // row_local in block
            const int row = ob + rl;
            const float4 v = *(const float4*)&w[(size_t)row * IN_F + kcg + 4 * lane];
            const float s = scale[row * NG + gb + (lane >> 5)];
            uint2 pk;
            pk.x = bfpack2(v.x * s, v.y * s);
            pk.y = bfpack2(v.z * s, v.w * s);
            // bytes: rl*528 + lane*8 -> 4 accesses/bank (minimal)
            *(uint2*)&wlds[rl * WSTRIDE + lane * 4] = pk;
        }
        __syncthreads();                        // w (and x, for c=0) staged

        // ---- compute: 8 MFMA steps over this chunk ----
#pragma unroll
        for (int tl = 0; tl < BK / 32; ++tl) {
            const int ts = c * (BK / 32) + tl;  // global step 0..15
            const bf16x8 afrag = *(const bf16x8*)&xswz[(ts * 64 + lane) * 8];
            // B[n=lane&15][k=tl*32+(lane>>4)*8+j]; bytes: row*528+tl*64+oct*16
            const bf16x8 bfrag = *(const bf16x8*)
                &wlds[(wv * 16 + (lane & 15)) * WSTRIDE + tl * 32 + (lane >> 4) * 8];
            acc = __builtin_amdgcn_mfma_f32_16x16x32_bf16(afrag, bfrag, acc, 0, 0, 0);
        }
    }

    // ---- epilogue: D[col=lane&15 -> row nrow][reg r -> batch (lane>>4)*4+r]
#pragma unroll
    for (int r = 0; r < 4; ++r) {
        const int b = (lane >> 4) * 4 + r;
        atomicAdd(&out[b * OUT_F + nrow], acc[r]);
    }
}

extern "C" void kernel_launch(void* const* d_in, const int* in_sizes, int n_in,
                              void* d_out, int out_size, void* d_ws, size_t ws_size,
                              hipStream_t stream) {
    const float* x    = (const float*)d_in[0];
    const float* w    = (const float*)d_in[1];
    const float* sc   = (const float*)d_in[2];
    const float* bias = (const float*)d_in[3];
    // d_in[4] = types: constant lookup, no float math -> unused
    float* out = (float*)d_out;

    hipLaunchKernelGGL(init_out_kernel, dim3(NB * OUT_F / 256), dim3(256),
                       0, stream, bias, out);
    hipLaunchKernelGGL(axcore_mfma_kernel, dim3(OUT_F / 64, KSPLIT), dim3(256),
                       0, stream, x, w, sc, out);
}